// Round 10
// baseline (298.585 us; speedup 1.0000x reference)
//
#include <hip/hip_runtime.h>
#include <hip/hip_fp16.h>

namespace {

constexpr int kFeat = 32;
constexpr int kNA = 64;
constexpr int kNE = 32;
constexpr int kGridElems = kFeat * kNA * kNE;   // 65536
constexpr int kPoleElems = kFeat * 2;           // 64
constexpr int kCols = kNA * kNE;                // 2048 grid columns
constexpr int kColS = kCols;                    // pole-south column index
constexpr int kColN = kCols + 1;                // pole-north column index
constexpr int kTotCols = kCols + 2;             // 2050

constexpr float kPi  = 3.14159265358979323846f;
constexpr float kPi2 = 1.57079632679489661923f;
constexpr float kOmegaAz = 0.09817477042468103f;   // 2*pi/64
constexpr float kOmegaEl = 0.09519977738150889f;   // pi/33
constexpr float kInvOmegaAz = 10.18591635788130f;  // 64/(2*pi)
constexpr float kInvOmegaEl = 10.50422624406509f;  // 33/pi
constexpr float kInvSinAz = 10.20229703f;          // 1/sin(2*pi/64)
constexpr float kInvSinEl = 10.52010966f;          // 1/sin(pi/33)

// Prepass: grid [F][A][E] fp32 -> gt [A*E + 2][F] fp16 (a feature column is
// one contiguous 64B cache line); poles appended as columns 2048/2049.
__global__ __launch_bounds__(256) void transpose_grid_h(
    const float* __restrict__ g, const float* __restrict__ poles,
    __half* __restrict__ gt) {
  int idx = blockIdx.x * 256 + threadIdx.x;
  if (idx < kGridElems) {
    int f = idx >> 11;       // / (NA*NE)
    int ae = idx & 2047;     // a*NE + e
    gt[ae * kFeat + f] = __float2half(g[idx]);
  }
  if (idx < kPoleElems) {
    int f = idx >> 1;
    int p = idx & 1;
    gt[(kCols + p) * kFeat + f] = __float2half(poles[idx]);
  }
}

struct PointSetup {
  int col_bl, col_br, col_tl, col_tr;
  float a1, a2, b1, b2;
};

__device__ __forceinline__ PointSetup setup_point(float az, float el) {
  PointSetup s;
  // azimuth bucket: ar = smallest k with tick_az[k] >= az; ticks at -pi + k*omega
  float ta = (az + kPi) * kInvOmegaAz;
  int ar0 = (int)ceilf(ta);
  int al = ar0 - 1;
  int ar = (ar0 >= kNA) ? 0 : ar0;
  if (al < 0) al = kNA - 1;
  float theta_a = az - (-kPi + (float)al * kOmegaAz);
  float w1a = __sinf(kOmegaAz - theta_a) * kInvSinAz;
  float w2a = __sinf(theta_a) * kInvSinAz;

  // elevation: er = searchsorted(interior ticks at -pi/2 + (k+1)*omega_el)
  float ue = (el + kPi2) * kInvOmegaEl;
  int er = (int)ceilf(ue) - 1;
  er = min(max(er, 0), kNE);
  bool south = (er == 0);
  bool north = (er == kNE);
  int eil = min(max(er - 1, 0), kNE - 1);
  int eir = min(er, kNE - 1);
  float base = south ? -kPi2 : (-kPi2 + (float)(eil + 1) * kOmegaEl);
  float theta_e = el - base;
  float w1e = __sinf(kOmegaEl - theta_e) * kInvSinEl;
  float w2e = __sinf(theta_e) * kInvSinEl;

  s.col_bl = al * kNE + eil;
  s.col_br = ar * kNE + eil;
  s.col_tl = al * kNE + eir;
  s.col_tr = ar * kNE + eir;
  s.a1 = w1e * w1a; s.a2 = w1e * w2a;
  s.b1 = w2e * w1a; s.b2 = w2e * w2a;
  // Pole redirect: exact pole value via two identical half-weight columns
  // (NORMALIZED=False, weights need not sum to 1).
  if (south) {
    s.col_bl = kColS; s.col_br = kColS;
    s.a1 = 0.5f * w1e; s.a2 = s.a1;
  }
  if (north) {
    s.col_tl = kColN; s.col_tr = kColN;
    s.b1 = 0.5f * w2e; s.b2 = s.b1;
  }
  return s;
}

// R9 champion (R4 structure + shuffle-dedup setup) made PERSISTENT:
// grid = 1280 blocks (5 resident/CU x 256 CUs); block b owns a CONTIGUOUS
// span of tiles [b*tpb, (b+1)*tpb). Its 32 per-feature-row write streams
// advance sequentially over ~7 KB each instead of 7 scattered 1 KB runs from
// 7 different short-lived blocks: better L2 evict clustering / DRAM page
// locality, and tile-0 pts/gather latency amortizes over the span.
// Gather shape (4 j-lanes per point read consecutive 16B quarters of a 64B
// column: 16 lines/instr -- load-bearing per R8), setup dedup via __shfl
// (R9), LDS tile + 1 KB-per-wave-store flush (R4, NT refuted twice) are all
// bit-identical to R9.
constexpr int kTile = 256;               // points per tile
constexpr int kTileFloats = kFeat * kTile;   // 8192 floats = 32 KiB LDS
constexpr int kBlocks = 1280;            // 5 blocks/CU x 256 CUs

__global__ __launch_bounds__(256) void interp_p(
    const float* __restrict__ pts, const __half* __restrict__ gt,
    float* __restrict__ out, int n, int tpb) {
  __shared__ float tile[kTileFloats];    // [feat][point], row-major
  const size_t sn = (size_t)n;
  const int t = threadIdx.x;
  const int w = t >> 6;                  // wave 0..3
  const int l = t & 63;                  // lane 0..63
  const int j = l & 3;
  const int off = j * 8;

  for (int tb = 0; tb < tpb; ++tb) {
    const int tile_idx = blockIdx.x * tpb + tb;
    const int base = tile_idx * kTile;
    if (base >= n) break;                // block-uniform: barrier-safe
    const int rem = min(kTile, n - base);

    // ---- setup phase: one setup per point, computed by its owner lane ----
    const int p_own = w * 16 + 64 * (l >> 4) + (l & 15);
    const int pc = min(p_own, rem - 1);  // clamp keeps all lanes shfl-active
    const float az = pts[base + pc];
    const float el = pts[n + base + pc];
    const PointSetup so = setup_point(az, el);

    // ---- compute phase: 4 c-iters, R4 slot mapping ----
#pragma unroll
    for (int c = 0; c < 4; ++c) {
      const int src = c * 16 + (l >> 2); // owner lane of this iter's point
      const int cbl = __shfl(so.col_bl, src);
      const int cbr = __shfl(so.col_br, src);
      const int ctl = __shfl(so.col_tl, src);
      const int ctr = __shfl(so.col_tr, src);
      const float a1 = __shfl(so.a1, src);
      const float a2 = __shfl(so.a2, src);
      const float b1 = __shfl(so.b1, src);
      const float b2 = __shfl(so.b2, src);
      const int p = w * 16 + 64 * c + (l >> 2);
      if (p < rem) {
        union H8 { uint4 u; __half2 h[4]; };
        H8 bl, br, tl, tr;
        bl.u = *(const uint4*)(gt + cbl * kFeat + off);
        br.u = *(const uint4*)(gt + cbr * kFeat + off);
        tl.u = *(const uint4*)(gt + ctl * kFeat + off);
        tr.u = *(const uint4*)(gt + ctr * kFeat + off);
        float* dst = tile + (8 * j) * kTile + p; // rows 8j..8j+7, column p
#pragma unroll
        for (int q = 0; q < 4; ++q) {
          float2 vbl = __half22float2(bl.h[q]);
          float2 vbr = __half22float2(br.h[q]);
          float2 vtl = __half22float2(tl.h[q]);
          float2 vtr = __half22float2(tr.h[q]);
          dst[(2 * q + 0) * kTile] =
              a1 * vbl.x + a2 * vbr.x + b1 * vtl.x + b2 * vtr.x;
          dst[(2 * q + 1) * kTile] =
              a1 * vbl.y + a2 * vbr.y + b1 * vtl.y + b2 * vtr.y;
        }
      }
    }

    __syncthreads();

    // ---- flush phase: LDS tile -> global, 1 KB contiguous per wave-store ----
    if (rem == kTile) {
#pragma unroll
      for (int r = 0; r < 8; ++r) {
        int u = t + 256 * r;
        int row = u >> 6;        // 64 lanes of a wave share one row
        int c4 = (u & 63) * 4;   // point offset within tile
        uint4 v = *(const uint4*)(tile + row * kTile + c4);
        *(uint4*)(out + (size_t)row * sn + base + c4) = v;
      }
    } else {
      // last partial tile: guarded element stores
      for (int r = 0; r < 8; ++r) {
        int u = t + 256 * r;
        int row = u >> 6;
        int c4 = (u & 63) * 4;
        float* o = out + (size_t)row * sn + base;
        for (int e = 0; e < 4; ++e) {
          int p = c4 + e;
          if (p < rem) o[p] = tile[row * kTile + p];
        }
      }
    }

    __syncthreads();             // tile reused next iteration
  }
}

// Fallback if the workspace is too small for the transposed fp16 grid:
// gather directly from the [F][A][E] layout (scalar strided loads).
__global__ __launch_bounds__(256) void interp_d(
    const float* __restrict__ pts, const float* __restrict__ g,
    const float* __restrict__ poles, float* __restrict__ out, int n) {
  int i = blockIdx.x * 256 + threadIdx.x;
  if (i >= n) return;
  float az = pts[i];
  float el = pts[n + i];
  PointSetup s = setup_point(az, el);

  float a1 = s.a1, a2 = s.a2, b1 = s.b1, b2 = s.b2;
  float pw0 = 0.0f, pw1 = 0.0f;
  if (s.col_bl == kColS) { pw0 = a1 + a2; a1 = 0.0f; a2 = 0.0f; }
  if (s.col_tl == kColN) { pw1 = b1 + b2; b1 = 0.0f; b2 = 0.0f; }

  const float* gbl = g + (s.col_bl < kCols ? s.col_bl : 0);
  const float* gbr = g + (s.col_br < kCols ? s.col_br : 0);
  const float* gtl = g + (s.col_tl < kCols ? s.col_tl : 0);
  const float* gtr = g + (s.col_tr < kCols ? s.col_tr : 0);
  size_t sn = (size_t)n;
#pragma unroll 8
  for (int f = 0; f < kFeat; ++f) {
    float v = a1 * gbl[f * kCols] + a2 * gbr[f * kCols]
            + b1 * gtl[f * kCols] + b2 * gtr[f * kCols]
            + pw0 * poles[f * 2 + 0] + pw1 * poles[f * 2 + 1];
    out[(size_t)f * sn + i] = v;
  }
}

}  // namespace

extern "C" void kernel_launch(void* const* d_in, const int* in_sizes, int n_in,
                              void* d_out, int out_size, void* d_ws, size_t ws_size,
                              hipStream_t stream) {
  (void)n_in; (void)out_size;
  const float* pts   = (const float*)d_in[0];
  const float* grid  = (const float*)d_in[1];
  const float* poles = (const float*)d_in[2];
  float* out = (float*)d_out;
  int n = in_sizes[0] / 2;

  size_t need = (size_t)(kTotCols * kFeat) * sizeof(__half);
  if (ws_size >= need) {
    __half* gt = (__half*)d_ws;
    transpose_grid_h<<<(kGridElems + 255) / 256, 256, 0, stream>>>(grid, poles, gt);
    int tiles = (n + kTile - 1) / kTile;
    int tpb = (tiles + kBlocks - 1) / kBlocks;   // contiguous tiles per block
    interp_p<<<kBlocks, 256, 0, stream>>>(pts, gt, out, n, tpb);
  } else {
    int blocks = (n + 255) / 256;
    interp_d<<<blocks, 256, 0, stream>>>(pts, grid, poles, out, n);
  }
}

// Round 11
// 277.480 us; speedup vs baseline: 1.0761x; 1.0761x over previous
//
#include <hip/hip_runtime.h>
#include <hip/hip_fp16.h>

namespace {

constexpr int kFeat = 32;
constexpr int kNA = 64;
constexpr int kNE = 32;
constexpr int kGridElems = kFeat * kNA * kNE;   // 65536
constexpr int kPoleElems = kFeat * 2;           // 64
constexpr int kCols = kNA * kNE;                // 2048 grid columns
constexpr int kColS = kCols;                    // pole-south column index
constexpr int kColN = kCols + 1;                // pole-north column index
constexpr int kTotCols = kCols + 2;             // 2050

constexpr float kPi  = 3.14159265358979323846f;
constexpr float kPi2 = 1.57079632679489661923f;
constexpr float kOmegaAz = 0.09817477042468103f;   // 2*pi/64
constexpr float kOmegaEl = 0.09519977738150889f;   // pi/33
constexpr float kInvOmegaAz = 10.18591635788130f;  // 64/(2*pi)
constexpr float kInvOmegaEl = 10.50422624406509f;  // 33/pi
constexpr float kInvSinAz = 10.20229703f;          // 1/sin(2*pi/64)
constexpr float kInvSinEl = 10.52010966f;          // 1/sin(pi/33)

// Prepass: grid [F][A][E] fp32 -> gt [A*E + 2][F] fp16 (a feature column is
// one contiguous 64B cache line); poles appended as columns 2048/2049.
__global__ __launch_bounds__(256) void transpose_grid_h(
    const float* __restrict__ g, const float* __restrict__ poles,
    __half* __restrict__ gt) {
  int idx = blockIdx.x * 256 + threadIdx.x;
  if (idx < kGridElems) {
    int f = idx >> 11;       // / (NA*NE)
    int ae = idx & 2047;     // a*NE + e
    gt[ae * kFeat + f] = __float2half(g[idx]);
  }
  if (idx < kPoleElems) {
    int f = idx >> 1;
    int p = idx & 1;
    gt[(kCols + p) * kFeat + f] = __float2half(poles[idx]);
  }
}

struct PointSetup {
  int col_bl, col_br, col_tl, col_tr;
  float a1, a2, b1, b2;
};

__device__ __forceinline__ PointSetup setup_point(float az, float el) {
  PointSetup s;
  // azimuth bucket: ar = smallest k with tick_az[k] >= az; ticks at -pi + k*omega
  float ta = (az + kPi) * kInvOmegaAz;
  int ar0 = (int)ceilf(ta);
  int al = ar0 - 1;
  int ar = (ar0 >= kNA) ? 0 : ar0;
  if (al < 0) al = kNA - 1;
  float theta_a = az - (-kPi + (float)al * kOmegaAz);
  float w1a = __sinf(kOmegaAz - theta_a) * kInvSinAz;
  float w2a = __sinf(theta_a) * kInvSinAz;

  // elevation: er = searchsorted(interior ticks at -pi/2 + (k+1)*omega_el)
  float ue = (el + kPi2) * kInvOmegaEl;
  int er = (int)ceilf(ue) - 1;
  er = min(max(er, 0), kNE);
  bool south = (er == 0);
  bool north = (er == kNE);
  int eil = min(max(er - 1, 0), kNE - 1);
  int eir = min(er, kNE - 1);
  float base = south ? -kPi2 : (-kPi2 + (float)(eil + 1) * kOmegaEl);
  float theta_e = el - base;
  float w1e = __sinf(kOmegaEl - theta_e) * kInvSinEl;
  float w2e = __sinf(theta_e) * kInvSinEl;

  s.col_bl = al * kNE + eil;
  s.col_br = ar * kNE + eil;
  s.col_tl = al * kNE + eir;
  s.col_tr = ar * kNE + eir;
  s.a1 = w1e * w1a; s.a2 = w1e * w2a;
  s.b1 = w2e * w1a; s.b2 = w2e * w2a;
  // Pole redirect: exact pole value via two identical half-weight columns
  // (NORMALIZED=False, weights need not sum to 1).
  if (south) {
    s.col_bl = kColS; s.col_br = kColS;
    s.a1 = 0.5f * w1e; s.a2 = s.a1;
  }
  if (north) {
    s.col_tl = kColN; s.col_tr = kColN;
    s.b1 = 0.5f * w2e; s.b2 = s.b1;
  }
  return s;
}

// R9 champion re-tiled to 512 points / 512 threads / 64 KiB LDS:
// per feature row each block now flushes one 2 KB contiguous run (vs 1 KB),
// halving the machine-wide count of interleaved write streams -- the next
// step on the only knob that has moved this kernel (64B->151us, 256B->144,
// 1KB->131, all else null). 2 blocks/CU (LDS-limited), 16 waves/CU -- the
// R0/R3 comparison showed this occupancy range is not binding.
// Unchanged from R9 (all proven load-bearing or neutral):
//  - gather shape: a point's 4 j-lanes read consecutive 16B quarters of each
//    64B column -> 16 distinct lines/instr (R8's own-point hit 64: +23us);
//  - setup dedup via __shfl from owner lane (R9: -8us);
//  - LDS tile + contiguous 128B-line-complete wave-stores, default-cached
//    (NT refuted in R1 and R7); non-persistent grid (R10 refuted spans).
constexpr int kTile = 512;                   // points per block
constexpr int kThreads = 512;                // 8 waves
constexpr int kTileFloats = kFeat * kTile;   // 16384 floats = 64 KiB LDS

__global__ __launch_bounds__(kThreads) void interp_s(
    const float* __restrict__ pts, const __half* __restrict__ gt,
    float* __restrict__ out, int n) {
  __shared__ float tile[kTileFloats];    // [feat][point], row-major
  const int base = blockIdx.x * kTile;
  const int rem = min(kTile, n - base);
  const size_t sn = (size_t)n;
  const int t = threadIdx.x;
  const int w = t >> 6;                  // wave 0..7
  const int l = t & 63;                  // lane 0..63
  const int j = l & 3;
  const int off = j * 8;

  // ---- setup phase: one setup per point, computed by its owner lane ----
  // wave w owns points w*16 + 128*k + m (k=l>>4 in 0..3, m=l&15): exactly the
  // 64 points wave w's 4 c-iters will process.
  const int p_own = w * 16 + 128 * (l >> 4) + (l & 15);
  const int pc = min(p_own, rem - 1);    // clamp keeps all lanes shfl-active
  const float az = pts[base + pc];
  const float el = pts[n + base + pc];
  const PointSetup so = setup_point(az, el);

  // ---- compute phase: 4 c-iters ----
#pragma unroll
  for (int c = 0; c < 4; ++c) {
    const int src = c * 16 + (l >> 2);   // owner lane of this iter's point
    const int cbl = __shfl(so.col_bl, src);
    const int cbr = __shfl(so.col_br, src);
    const int ctl = __shfl(so.col_tl, src);
    const int ctr = __shfl(so.col_tr, src);
    const float a1 = __shfl(so.a1, src);
    const float a2 = __shfl(so.a2, src);
    const float b1 = __shfl(so.b1, src);
    const float b2 = __shfl(so.b2, src);
    const int p = w * 16 + 128 * c + (l >> 2);
    if (p < rem) {
      union H8 { uint4 u; __half2 h[4]; };
      H8 bl, br, tl, tr;
      bl.u = *(const uint4*)(gt + cbl * kFeat + off);
      br.u = *(const uint4*)(gt + cbr * kFeat + off);
      tl.u = *(const uint4*)(gt + ctl * kFeat + off);
      tr.u = *(const uint4*)(gt + ctr * kFeat + off);
      float* dst = tile + (8 * j) * kTile + p;   // rows 8j..8j+7, column p
#pragma unroll
      for (int q = 0; q < 4; ++q) {
        float2 vbl = __half22float2(bl.h[q]);
        float2 vbr = __half22float2(br.h[q]);
        float2 vtl = __half22float2(tl.h[q]);
        float2 vtr = __half22float2(tr.h[q]);
        dst[(2 * q + 0) * kTile] =
            a1 * vbl.x + a2 * vbr.x + b1 * vtl.x + b2 * vtr.x;
        dst[(2 * q + 1) * kTile] =
            a1 * vbl.y + a2 * vbr.y + b1 * vtl.y + b2 * vtr.y;
      }
    }
  }

  __syncthreads();

  // ---- flush phase: LDS tile -> global ----
  // tile = 4096 uint4; u = t + 512*r; row = u>>7 (128 uint4 per row),
  // col = u&127. Two consecutive waves cover one full 2 KB row run.
  if (rem == kTile) {
#pragma unroll
    for (int r = 0; r < 8; ++r) {
      int u = t + kThreads * r;
      int row = u >> 7;
      int c4 = (u & 127) * 4;    // point offset within tile
      uint4 v = *(const uint4*)(tile + row * kTile + c4);
      *(uint4*)(out + (size_t)row * sn + base + c4) = v;
    }
  } else {
    // last partial tile: guarded element stores
    for (int r = 0; r < 8; ++r) {
      int u = t + kThreads * r;
      int row = u >> 7;
      int c4 = (u & 127) * 4;
      float* o = out + (size_t)row * sn + base;
      for (int e = 0; e < 4; ++e) {
        int p = c4 + e;
        if (p < rem) o[p] = tile[row * kTile + p];
      }
    }
  }
}

// Fallback if the workspace is too small for the transposed fp16 grid:
// gather directly from the [F][A][E] layout (scalar strided loads).
__global__ __launch_bounds__(256) void interp_d(
    const float* __restrict__ pts, const float* __restrict__ g,
    const float* __restrict__ poles, float* __restrict__ out, int n) {
  int i = blockIdx.x * 256 + threadIdx.x;
  if (i >= n) return;
  float az = pts[i];
  float el = pts[n + i];
  PointSetup s = setup_point(az, el);

  float a1 = s.a1, a2 = s.a2, b1 = s.b1, b2 = s.b2;
  float pw0 = 0.0f, pw1 = 0.0f;
  if (s.col_bl == kColS) { pw0 = a1 + a2; a1 = 0.0f; a2 = 0.0f; }
  if (s.col_tl == kColN) { pw1 = b1 + b2; b1 = 0.0f; b2 = 0.0f; }

  const float* gbl = g + (s.col_bl < kCols ? s.col_bl : 0);
  const float* gbr = g + (s.col_br < kCols ? s.col_br : 0);
  const float* gtl = g + (s.col_tl < kCols ? s.col_tl : 0);
  const float* gtr = g + (s.col_tr < kCols ? s.col_tr : 0);
  size_t sn = (size_t)n;
#pragma unroll 8
  for (int f = 0; f < kFeat; ++f) {
    float v = a1 * gbl[f * kCols] + a2 * gbr[f * kCols]
            + b1 * gtl[f * kCols] + b2 * gtr[f * kCols]
            + pw0 * poles[f * 2 + 0] + pw1 * poles[f * 2 + 1];
    out[(size_t)f * sn + i] = v;
  }
}

}  // namespace

extern "C" void kernel_launch(void* const* d_in, const int* in_sizes, int n_in,
                              void* d_out, int out_size, void* d_ws, size_t ws_size,
                              hipStream_t stream) {
  (void)n_in; (void)out_size;
  const float* pts   = (const float*)d_in[0];
  const float* grid  = (const float*)d_in[1];
  const float* poles = (const float*)d_in[2];
  float* out = (float*)d_out;
  int n = in_sizes[0] / 2;

  size_t need = (size_t)(kTotCols * kFeat) * sizeof(__half);
  if (ws_size >= need) {
    __half* gt = (__half*)d_ws;
    transpose_grid_h<<<(kGridElems + 255) / 256, 256, 0, stream>>>(grid, poles, gt);
    int blocks = (n + kTile - 1) / kTile;
    interp_s<<<blocks, kThreads, 0, stream>>>(pts, gt, out, n);
  } else {
    int blocks = (n + 255) / 256;
    interp_d<<<blocks, 256, 0, stream>>>(pts, grid, poles, out, n);
  }
}